// Round 1
// baseline (100.942 us; speedup 1.0000x reference)
//
#include <hip/hip_runtime.h>
#include <hip/hip_bf16.h>

// Problem constants (fixed by the reference):
//   B=16, T=1024 -> BT=16384 rows; C=512 phones; A=4096 arcs; P=256 phonemes.
#define BT   16384
#define CDIM 512
#define ADIM 4096
#define PDIM 256

typedef __attribute__((ext_vector_type(8))) short short8;  // 8 x bf16 (4 VGPRs)
typedef __attribute__((ext_vector_type(4))) float f32x4;   // 4 x fp32 acc

// fp32 -> bf16 round-to-nearest-even (values are positive finite)
__device__ __forceinline__ unsigned short bf16_rne(float f) {
    unsigned int u = __float_as_uint(f);
    u += 0x7FFFu + ((u >> 16) & 1u);
    return (unsigned short)(u >> 16);
}

// ---------------------------------------------------------------------------
// Kernel 1 (unchanged): one block per phone c. Scan all arcs, accumulate
// W[c][p] = sum_{a: phone=c, phoneme=p} exp(alloW[a]) in LDS, then emit
// bf16 B-fragment-major layout: Wf[kb][n][kin], kb=c>>5, kin=c&31.
// ---------------------------------------------------------------------------
__global__ __launch_bounds__(256) void build_Wf(const float* __restrict__ alloW,
                                                const int* __restrict__ phone_lab,
                                                const int* __restrict__ phoneme_lab,
                                                unsigned short* __restrict__ Wf) {
    __shared__ float wrow[PDIM];
    const int c = blockIdx.x;
    const int t = threadIdx.x;
    wrow[t] = 0.0f;
    __syncthreads();
#pragma unroll
    for (int i = 0; i < ADIM / 256; ++i) {
        int a = i * 256 + t;
        if (phone_lab[a] == c)
            atomicAdd(&wrow[phoneme_lab[a]], __expf(alloW[a]));
    }
    __syncthreads();
    Wf[(c >> 5) * (PDIM * 32) + t * 32 + (c & 31)] = bf16_rne(wrow[t]);
}

// ---------------------------------------------------------------------------
// Kernel 2: fused exp + GEMM + redistribute + log.
// CHANGE vs 99.1us version: 512-thread blocks (8 waves) on the same
// 32-row x 256-col tile. Grid stays 512 (= 2 blocks/CU) but waves/CU
// doubles 8 -> 16 (25% -> 50% occupancy). Total HBM/L2/LDS traffic is
// unchanged; per-wave work halves. Theory: kernel is latency-bound at
// 2 waves/SIMD; more resident waves hide L2 latency + barrier drains.
//
// Prologue: 16 threads/row read the row's 512 logits (coalesced float4),
// compute e=exp(x), rowsum Z via 16-lane shfl, store bf16 e into LDS in
// A-fragment layout Af[rb][kb][cc][kin]. 1/Z applied in epilogue.
//
// K-loop: per wave per kb: 2 LDS A-frags, 2 global B-frags (L2-hot),
// 4 MFMA 16x16x32. Wave w owns output cols [w*32, w*32+32).
// ---------------------------------------------------------------------------
__global__ __launch_bounds__(512, 4) void allo_fused(const float* __restrict__ hs,
                                                     const unsigned short* __restrict__ Wf,
                                                     float* __restrict__ out) {
    __shared__ __align__(16) unsigned short Af[2 * 16 * 16 * 32];  // 32 KB
    __shared__ float invZ[32];
    __shared__ float psum[8][32];

    const int tid  = threadIdx.x;
    const int row0 = blockIdx.x * 32;

    // ---- prologue: stage bf16 e-values in A-frag layout, compute invZ ----
    {
        const int r   = tid >> 4;        // 0..31 (row within tile)
        const int ksl = tid & 15;        // 0..15 (16B slice within row)
        const int rb  = r >> 4;
        const int cc  = r & 15;
        const float* hsr = hs + (size_t)(row0 + r) * CDIM + ksl * 4;
        // column c_glob = i*64 + ksl*4 + j  ->  kb = 2*i + (ksl>>3),
        // kin = (ksl&7)*4 + j.  Af index = rb*8192 + kb*512 + cc*32 + kin.
        unsigned short* af = Af + rb * 8192 + (ksl >> 3) * 512 + cc * 32 + (ksl & 7) * 4;

        float s = 0.0f;
#pragma unroll
        for (int i = 0; i < 8; ++i) {
            float4 v = *(const float4*)(hsr + i * 64);
            float e0 = __expf(v.x), e1 = __expf(v.y);
            float e2 = __expf(v.z), e3 = __expf(v.w);
            s += (e0 + e1) + (e2 + e3);
            ushort4 pk;
            pk.x = bf16_rne(e0); pk.y = bf16_rne(e1);
            pk.z = bf16_rne(e2); pk.w = bf16_rne(e3);
            *(ushort4*)(af + i * 1024) = pk;
        }
        // reduce Z over the 16 lanes of this row (contiguous lanes, same wave)
        s += __shfl_xor(s, 1);
        s += __shfl_xor(s, 2);
        s += __shfl_xor(s, 4);
        s += __shfl_xor(s, 8);
        if (ksl == 0) invZ[r] = 1.0f / s;
    }
    __syncthreads();

    // ---- MFMA K-loop ----
    const int wave = tid >> 6;   // 0..7
    const int lane = tid & 63;
    const int c    = lane & 15;
    const int q    = lane >> 4;

    f32x4 acc[2][2];
#pragma unroll
    for (int rb = 0; rb < 2; ++rb)
#pragma unroll
        for (int cb = 0; cb < 2; ++cb)
            acc[rb][cb] = (f32x4){0.f, 0.f, 0.f, 0.f};

    const unsigned short* wb  = Wf + (size_t)(wave * 32 + c) * 32 + q * 8;
    const unsigned short* af0 = Af + c * 32 + q * 8;

#pragma unroll 4
    for (int kb = 0; kb < 16; ++kb) {
        short8 a0 = *(const short8*)(af0 + kb * 512);
        short8 a1 = *(const short8*)(af0 + 8192 + kb * 512);

        const unsigned short* wkb = wb + kb * 8192;
        short8 b0 = *(const short8*)(wkb);
        short8 b1 = *(const short8*)(wkb + 512);

        acc[0][0] = __builtin_amdgcn_mfma_f32_16x16x32_bf16(a0, b0, acc[0][0], 0, 0, 0);
        acc[0][1] = __builtin_amdgcn_mfma_f32_16x16x32_bf16(a0, b1, acc[0][1], 0, 0, 0);
        acc[1][0] = __builtin_amdgcn_mfma_f32_16x16x32_bf16(a1, b0, acc[1][0], 0, 0, 0);
        acc[1][1] = __builtin_amdgcn_mfma_f32_16x16x32_bf16(a1, b1, acc[1][1], 0, 0, 0);
    }

    // ---- epilogue ----
    // C/D mapping (m89/m91): col = lane&15 (=c), row = q*4 + reg.
    float sp[2][4];
#pragma unroll
    for (int rb = 0; rb < 2; ++rb)
#pragma unroll
        for (int r = 0; r < 4; ++r) {
            float v = acc[rb][0][r] + acc[rb][1][r];
            v += __shfl_xor(v, 1);
            v += __shfl_xor(v, 2);
            v += __shfl_xor(v, 4);
            v += __shfl_xor(v, 8);
            sp[rb][r] = v;   // this wave's 32-col partial for row rb*16+q*4+r
        }
    if (c == 0) {
#pragma unroll
        for (int rb = 0; rb < 2; ++rb)
#pragma unroll
            for (int r = 0; r < 4; ++r)
                psum[wave][rb * 16 + q * 4 + r] = sp[rb][r];
    }
    __syncthreads();

#pragma unroll
    for (int rb = 0; rb < 2; ++rb)
#pragma unroll
        for (int r = 0; r < 4; ++r) {
            const int rr  = rb * 16 + q * 4 + r;
            const float iz = invZ[rr];
            float Ssum = 0.0f;
#pragma unroll
            for (int w = 0; w < 8; ++w) Ssum += psum[w][rr];
            const float S    = Ssum * iz;
            const float corr = (S - 1.0f) * (1.0f / (float)PDIM);
            float* orow = out + (size_t)(row0 + rr) * PDIM + wave * 32 + c;
            orow[0]  = __logf(acc[rb][0][r] * iz - corr);
            orow[16] = __logf(acc[rb][1][r] * iz - corr);
        }
}

// ---------------------------------------------------------------------------
extern "C" void kernel_launch(void* const* d_in, const int* in_sizes, int n_in,
                              void* d_out, int out_size, void* d_ws, size_t ws_size,
                              hipStream_t stream) {
    const float* hs          = (const float*)d_in[0];  // [BT, C]
    const float* alloW       = (const float*)d_in[1];  // [A]
    const int*   phone_lab   = (const int*)d_in[2];    // [A]
    const int*   phoneme_lab = (const int*)d_in[3];    // [A]
    float*       out         = (float*)d_out;          // [BT, P]

    unsigned short* Wf = (unsigned short*)d_ws;        // 256 KB, fully rewritten

    build_Wf<<<CDIM, 256, 0, stream>>>(alloW, phone_lab, phoneme_lab, Wf);
    allo_fused<<<BT / 32, 512, 0, stream>>>(hs, Wf, out);
}

// Round 2
// 100.453 us; speedup vs baseline: 1.0049x; 1.0049x over previous
//
#include <hip/hip_runtime.h>
#include <hip/hip_bf16.h>

// Problem constants (fixed by the reference):
//   B=16, T=1024 -> BT=16384 rows; C=512 phones; A=4096 arcs; P=256 phonemes.
#define BT   16384
#define CDIM 512
#define ADIM 4096
#define PDIM 256

typedef __attribute__((ext_vector_type(8))) short short8;  // 8 x bf16 (4 VGPRs)
typedef __attribute__((ext_vector_type(4))) float f32x4;   // 4 x fp32 acc

// fp32 -> bf16 round-to-nearest-even (values are positive finite)
__device__ __forceinline__ unsigned short bf16_rne(float f) {
    unsigned int u = __float_as_uint(f);
    u += 0x7FFFu + ((u >> 16) & 1u);
    return (unsigned short)(u >> 16);
}

// ---------------------------------------------------------------------------
// Kernel 1: one block per phone c. Scan all arcs, accumulate
// W[c][p] = sum_{a: phone=c, phoneme=p} exp(alloW[a]) in LDS, then emit
// bf16 B-fragment-major layout: Wf[kb][slot][kin], kb=c>>5, kin=c&31.
// CHANGE: slot order within each 32-col group is interleaved
//   slot(p) = ((p&1)<<4) | ((p&31)>>1)
// so that MFMA fragment-pair (b0,b1) for lane c covers ADJACENT output
// columns (2c, 2c+1) -> float2 epilogue stores, 128B-contiguous per wave.
// ---------------------------------------------------------------------------
__global__ __launch_bounds__(256) void build_Wf(const float* __restrict__ alloW,
                                                const int* __restrict__ phone_lab,
                                                const int* __restrict__ phoneme_lab,
                                                unsigned short* __restrict__ Wf) {
    __shared__ float wrow[PDIM];
    const int c = blockIdx.x;
    const int t = threadIdx.x;
    wrow[t] = 0.0f;
    __syncthreads();
#pragma unroll
    for (int i = 0; i < ADIM / 256; ++i) {
        int a = i * 256 + t;
        if (phone_lab[a] == c)
            atomicAdd(&wrow[phoneme_lab[a]], __expf(alloW[a]));
    }
    __syncthreads();
    // column-slot permutation within the 32-col group (see header comment)
    const int slot = (t & ~31) | ((t & 1) << 4) | ((t & 31) >> 1);
    Wf[(c >> 5) * (PDIM * 32) + slot * 32 + (c & 31)] = bf16_rne(wrow[t]);
}

// ---------------------------------------------------------------------------
// Kernel 2: fused exp + GEMM + redistribute + log.
// 512-thread blocks (8 waves) on a 32-row x 256-col tile; grid 512.
// CHANGES vs Round 0:
//  - B-fragment loads for kb=0 issued BEFORE the prologue barrier (they only
//    depend on global Wf), register-rotated through a fully unrolled K-loop.
//  - epilogue writes float2 per lane (adjacent cols 2c,2c+1 via the Wf slot
//    permutation) -> 128B contiguous wave segments instead of dword scatter.
// ---------------------------------------------------------------------------
__global__ __launch_bounds__(512, 4) void allo_fused(const float* __restrict__ hs,
                                                     const unsigned short* __restrict__ Wf,
                                                     float* __restrict__ out) {
    __shared__ __align__(16) unsigned short Af[2 * 16 * 16 * 32];  // 32 KB
    __shared__ float invZ[32];
    __shared__ float psum[8][32];

    const int tid  = threadIdx.x;
    const int row0 = blockIdx.x * 32;

    // wave/lane geometry needed for the B prefetch (independent of prologue)
    const int wave = tid >> 6;   // 0..7
    const int lane = tid & 63;
    const int c    = lane & 15;
    const int q    = lane >> 4;

    const unsigned short* wb  = Wf + (size_t)(wave * 32 + c) * 32 + q * 8;
    const unsigned short* af0 = Af + c * 32 + q * 8;

    // prefetch B fragments for kb=0 before the staging barrier
    short8 nb0 = *(const short8*)(wb);
    short8 nb1 = *(const short8*)(wb + 512);

    // ---- prologue: stage bf16 e-values in A-frag layout, compute invZ ----
    {
        const int r   = tid >> 4;        // 0..31 (row within tile)
        const int ksl = tid & 15;        // 0..15 (16B slice within row)
        const int rb  = r >> 4;
        const int cc  = r & 15;
        const float* hsr = hs + (size_t)(row0 + r) * CDIM + ksl * 4;
        // column c_glob = i*64 + ksl*4 + j  ->  kb = 2*i + (ksl>>3),
        // kin = (ksl&7)*4 + j.  Af index = rb*8192 + kb*512 + cc*32 + kin.
        unsigned short* af = Af + rb * 8192 + (ksl >> 3) * 512 + cc * 32 + (ksl & 7) * 4;

        float s = 0.0f;
#pragma unroll
        for (int i = 0; i < 8; ++i) {
            float4 v = *(const float4*)(hsr + i * 64);
            float e0 = __expf(v.x), e1 = __expf(v.y);
            float e2 = __expf(v.z), e3 = __expf(v.w);
            s += (e0 + e1) + (e2 + e3);
            ushort4 pk;
            pk.x = bf16_rne(e0); pk.y = bf16_rne(e1);
            pk.z = bf16_rne(e2); pk.w = bf16_rne(e3);
            *(ushort4*)(af + i * 1024) = pk;
        }
        // reduce Z over the 16 lanes of this row (contiguous lanes, same wave)
        s += __shfl_xor(s, 1);
        s += __shfl_xor(s, 2);
        s += __shfl_xor(s, 4);
        s += __shfl_xor(s, 8);
        if (ksl == 0) invZ[r] = 1.0f / s;
    }
    __syncthreads();

    // ---- MFMA K-loop (full unroll, register-rotated B) ----
    f32x4 acc[2][2];
#pragma unroll
    for (int rb = 0; rb < 2; ++rb)
#pragma unroll
        for (int cb = 0; cb < 2; ++cb)
            acc[rb][cb] = (f32x4){0.f, 0.f, 0.f, 0.f};

#pragma unroll
    for (int kb = 0; kb < 16; ++kb) {
        short8 b0 = nb0;
        short8 b1 = nb1;
        if (kb < 15) {
            const unsigned short* wkb = wb + (kb + 1) * 8192;
            nb0 = *(const short8*)(wkb);
            nb1 = *(const short8*)(wkb + 512);
        }
        short8 a0 = *(const short8*)(af0 + kb * 512);
        short8 a1 = *(const short8*)(af0 + 8192 + kb * 512);

        acc[0][0] = __builtin_amdgcn_mfma_f32_16x16x32_bf16(a0, b0, acc[0][0], 0, 0, 0);
        acc[0][1] = __builtin_amdgcn_mfma_f32_16x16x32_bf16(a0, b1, acc[0][1], 0, 0, 0);
        acc[1][0] = __builtin_amdgcn_mfma_f32_16x16x32_bf16(a1, b0, acc[1][0], 0, 0, 0);
        acc[1][1] = __builtin_amdgcn_mfma_f32_16x16x32_bf16(a1, b1, acc[1][1], 0, 0, 0);
    }

    // ---- epilogue ----
    // C/D mapping (m89/m91): col-slot = lane&15 (=c), row = q*4 + reg.
    // With the Wf slot permutation: acc[rb][0][r] -> col wave*32 + 2c,
    //                               acc[rb][1][r] -> col wave*32 + 2c + 1.
    float sp[2][4];
#pragma unroll
    for (int rb = 0; rb < 2; ++rb)
#pragma unroll
        for (int r = 0; r < 4; ++r) {
            float v = acc[rb][0][r] + acc[rb][1][r];
            v += __shfl_xor(v, 1);
            v += __shfl_xor(v, 2);
            v += __shfl_xor(v, 4);
            v += __shfl_xor(v, 8);
            sp[rb][r] = v;   // this wave's 32-col partial for row rb*16+q*4+r
        }
    if (c == 0) {
#pragma unroll
        for (int rb = 0; rb < 2; ++rb)
#pragma unroll
            for (int r = 0; r < 4; ++r)
                psum[wave][rb * 16 + q * 4 + r] = sp[rb][r];
    }
    __syncthreads();

#pragma unroll
    for (int rb = 0; rb < 2; ++rb)
#pragma unroll
        for (int r = 0; r < 4; ++r) {
            const int rr  = rb * 16 + q * 4 + r;
            const float iz = invZ[rr];
            float Ssum = 0.0f;
#pragma unroll
            for (int w = 0; w < 8; ++w) Ssum += psum[w][rr];
            const float S    = Ssum * iz;
            const float corr = (S - 1.0f) * (1.0f / (float)PDIM);
            float2 o;
            o.x = __logf(acc[rb][0][r] * iz - corr);
            o.y = __logf(acc[rb][1][r] * iz - corr);
            *(float2*)(out + (size_t)(row0 + rr) * PDIM + wave * 32 + 2 * c) = o;
        }
}

// ---------------------------------------------------------------------------
extern "C" void kernel_launch(void* const* d_in, const int* in_sizes, int n_in,
                              void* d_out, int out_size, void* d_ws, size_t ws_size,
                              hipStream_t stream) {
    const float* hs          = (const float*)d_in[0];  // [BT, C]
    const float* alloW       = (const float*)d_in[1];  // [A]
    const int*   phone_lab   = (const int*)d_in[2];    // [A]
    const int*   phoneme_lab = (const int*)d_in[3];    // [A]
    float*       out         = (float*)d_out;          // [BT, P]

    unsigned short* Wf = (unsigned short*)d_ws;        // 256 KB, fully rewritten

    build_Wf<<<CDIM, 256, 0, stream>>>(alloW, phone_lab, phoneme_lab, Wf);
    allo_fused<<<BT / 32, 512, 0, stream>>>(hs, Wf, out);
}